// Round 15
// baseline (8097.158 us; speedup 1.0000x reference)
//
#include <hip/hip_runtime.h>
#include <stdint.h>

// SpikingNetwork B=128 T=128 I=1024 dims 2048/2048/1024, beta=0.9, thr=1.0.
// R19: R11 (6.31ms best) with B moved OFF the LDS pipe. R11 is at ~95% of the
// measured ds_read_b128 ceiling (m134); R16/R17/R18 all failed to cut LDS
// instrs without a larger hidden cost. R19 deletes lB entirely: the FMA loop
// reads W directly from global — 16-lane broadcast per tn, linear walk, W is
// L3-resident (32MB < 256MB) and L1/L2-hot (64 rows x 512B per chunk = 32KB
// = L1, shared by the block's 8 waves). LDS-pipe demand halves (8192->4096
// reads/CU/t); B-staging (ds_writes + global staging loads + addr VALU) gone;
// the barrier-guarded staging phase is A-only. All else R11-verbatim:
// 256 blk x 512 thr (2 waves/SIMD), 64x64 tiles, 4m x 4n/thread, L0 ksplit2
// in-block, L1/L2 ksplit4 = 2 in-block + cross-block pair, single-buffered
// global partials + tid0-spun coarse flags. DAG bit-identical: same B values
// from the same memory, per-output 512-k ascending fmac chains,
// ((P0+P1)+P2)+P3 __fadd_rn merges in order, LIF rounding verbatim.

#define TT   128
#define NB   128
#define DD2  1024

// ws layout (u32 units) — identical to R11 (proven)
#define SPK0_OFF 0u
#define SPK1_OFF (128u*128u*64u)                 // 1,048,576
#define PART_OFF (2u*128u*128u*64u)              // 2,097,152
#define NHELP    96u                             // 96 slots x 8192 floats (32KB)
#define FLG_OFF  (PART_OFF + NHELP*8192u)        // 2,883,584
#define NFLG     1536u                           // pflag512 oflag512 done0 2x128 done1 2x128
#define WS_NEED_BYTES ((size_t)(FLG_OFF + NFLG) * 4u)   // 11,540,480

__device__ __forceinline__ void wait_ge(uint32_t* p, uint32_t tgt){
  while (__hip_atomic_load(p, __ATOMIC_ACQUIRE, __HIP_MEMORY_SCOPE_AGENT) < tgt)
    __builtin_amdgcn_s_sleep(1);
}

// LDS column swizzle for lA (R11-verbatim): 4-float granules, constant over a
// 4-aligned k-granule.
__device__ __forceinline__ constexpr int fswz(int k){
  return (k & 16) | ((k ^ (k >> 3)) & 12);
}

__global__ void sentinel_kernel(float* o){ o[0] = 42.0f; }   // ws-too-small marker

__global__ __launch_bounds__(512, 2) void snn_kernel(
    const float* __restrict__ x,
    const float* __restrict__ W0, const float* __restrict__ b0,
    const float* __restrict__ W1, const float* __restrict__ b1,
    const float* __restrict__ W2, const float* __restrict__ b2,
    float* __restrict__ out, uint32_t* __restrict__ ws)
{
  __shared__ __align__(16) float lA[2][128][68];   // per-half [k][m^swz], 69,632 B
  __shared__ uint32_t lBits[128];                  // 64 rows x 2 words
  // total ~70.1 KB; grid 256 -> 1 block/CU, 8 waves/CU (2/SIMD), as R11

  const int tid  = threadIdx.x;
  const int h    = tid >> 8;       // half: k-part within block
  const int t256 = tid & 255;
  const int tm   = t256 & 15;      // m-group: rows tm*4 .. +3
  const int tn   = t256 >> 4;      // n-group: cols tn*4 .. +3
  const int bid  = blockIdx.x;

  uint32_t* spikes0  = ws + SPK0_OFF;
  uint32_t* spikes1  = ws + SPK1_OFF;
  float*    partials = (float*)(ws + PART_OFF);   // [NHELP][8192]
  uint32_t* flg   = ws + FLG_OFF;
  uint32_t* pflag = flg;            // [512] helper(bid)->owner: partials for t ready
  uint32_t* oflag = flg + 512;      // [512] owner(bid)->helper: consumed through t
  uint32_t* done0 = flg + 1024;     // [2][128] per m-half, target 32
  uint32_t* done1 = flg + 1280;     // [2][128] per m-half, target 32

  int group, pairk, tl, m0, n0, K, hslot;
  const float *Wl, *bl;
  const uint32_t* spkIn; uint32_t* spkOut;
  uint32_t *dIn, *dOut;
  if (bid < 64) {           // L0: 64 tiles 64x64, K=1024, ksplit2 in-block
    group=0; pairk=0; tl=bid;
    m0=(tl>>5)*64; n0=(tl&31)*64; K=1024; Wl=W0; bl=b0;
    spkIn=nullptr; spkOut=spikes0; dIn=nullptr; dOut=done0+(m0>>6)*128; hslot=-1;
  } else if (bid < 192) {   // L1: 64 tiles 64x64, K=2048, ksplit4 (2 blocks/tile)
    group=1; int rel=bid-64; pairk=rel&1; tl=rel>>1;
    m0=(tl>>5)*64; n0=(tl&31)*64; K=2048; Wl=W1; bl=b1;
    spkIn=spikes0; spkOut=spikes1;
    dIn=done0+(m0>>6)*128; dOut=done1+(m0>>6)*128; hslot=tl;
  } else {                  // L2: 32 tiles 64x64, K=2048, ksplit4
    group=2; int rel=bid-192; pairk=rel&1; tl=rel>>1;
    m0=(tl>>4)*64; n0=(tl&15)*64; K=2048; Wl=W2; bl=b2;
    spkIn=spikes1; spkOut=nullptr;
    dIn=done1+(m0>>6)*128; dOut=nullptr; hslot=64+tl;
  }
  const bool helper = (pairk == 1);   // odd block of a pair: ships P2,P3
  const int  K0     = (pairk*2 + h)*512;

  float bias[4];
  #pragma unroll
  for (int c = 0; c < 4; ++c) bias[c] = bl[n0 + tn*4 + c];

  // B row pointers: each thread's 4 n-rows, offset by its k-part base.
  // 16 lanes share tn -> broadcast loads; rows walk linearly in k (L1/L2-hot).
  const float* pB0 = Wl + (size_t)(n0 + tn*4 + 0)*K + K0;
  const float* pB1 = Wl + (size_t)(n0 + tn*4 + 1)*K + K0;
  const float* pB2 = Wl + (size_t)(n0 + tn*4 + 2)*K + K0;
  const float* pB3 = Wl + (size_t)(n0 + tn*4 + 3)*K + K0;

  float vst[4][4];   // membrane potential (owner h=0 threads)
  #pragma unroll
  for (int r = 0; r < 4; ++r)
    #pragma unroll
    for (int c = 0; c < 4; ++c) vst[r][c] = 0.f;

  // spike-expansion mapping (R11 verbatim): 4 rows x 8 k per thread
  const int e_mq   = t256 & 15;
  const int e_sub  = t256 >> 4;
  const int e_wsub = e_sub & 3;
  const int e_kq8  = e_sub >> 2;
  const int e_kloc = e_wsub*32 + e_kq8*8;

  float (*cA)[68] = lA[h];
  float* ex = &lA[1][0][0];   // in-block merge buffer (16KB of half-1 lA)

  for (int t = 0; t < TT; ++t) {
    if (dIn) {  // previous layer's spikes for this m-half must be complete
      if (tid == 0) wait_ge(&dIn[t], 32u);
      __syncthreads();
    }

    float acc[4][4];   // ONE 512-k chain per half
    #pragma unroll
    for (int r = 0; r < 4; ++r)
      #pragma unroll
      for (int c = 0; c < 4; ++c) acc[r][c] = 0.f;

    #pragma unroll 1
    for (int ch = 0; ch < 4; ++ch) {            // 4 chunks of 128 k
      const int kb = K0 + ch*128;               // global k base
      const int kl = ch*128;                    // k offset within this 512-part

      // ---- stage A only (B is global-direct now)
      if (group == 0) {       // x[b,t,k] -> lA[k][m^swz]
        #pragma unroll
        for (int it = 0; it < 8; ++it) {
          int idx = t256 + it*256;
          int mrow = idx >> 5, kq = idx & 31;
          float4 v = *(const float4*)(x + ((size_t)(m0+mrow)*TT + t)*1024 + kb + kq*4);
          int k0 = kq*4;
          const int sw = fswz(k0);
          const int col = mrow ^ sw;
          cA[k0+0][col] = v.x; cA[k0+1][col] = v.y;
          cA[k0+2][col] = v.z; cA[k0+3][col] = v.w;
        }
      } else {                // spike bits -> {0,1} f32; 4 rows x 8 k per thread
        const size_t rbase = ((size_t)t*NB + m0 + e_mq*4)*64 + (kb>>5) + e_wsub;
        uint32_t w0 = __hip_atomic_load(&spkIn[rbase      ], __ATOMIC_RELAXED, __HIP_MEMORY_SCOPE_AGENT);
        uint32_t w1 = __hip_atomic_load(&spkIn[rbase +  64], __ATOMIC_RELAXED, __HIP_MEMORY_SCOPE_AGENT);
        uint32_t w2 = __hip_atomic_load(&spkIn[rbase + 128], __ATOMIC_RELAXED, __HIP_MEMORY_SCOPE_AGENT);
        uint32_t w3 = __hip_atomic_load(&spkIn[rbase + 192], __ATOMIC_RELAXED, __HIP_MEMORY_SCOPE_AGENT);
        #pragma unroll
        for (int i = 0; i < 8; ++i) {
          int k  = e_kloc + i;
          int sh = k & 31;
          float4 f;
          f.x = ((w0 >> sh) & 1u) ? 1.0f : 0.0f;
          f.y = ((w1 >> sh) & 1u) ? 1.0f : 0.0f;
          f.z = ((w2 >> sh) & 1u) ? 1.0f : 0.0f;
          f.w = ((w3 >> sh) & 1u) ? 1.0f : 0.0f;
          *(float4*)&cA[k][(e_mq*4) ^ fswz(k)] = f;
        }
      }
      __syncthreads();

      // ---- FMA micro-kernel: 128 k x (4m x 4n), ascending k.
      //      A from LDS; B direct from global (L1/L2-hot, lane-broadcast).
      #pragma unroll 4
      for (int k4 = 0; k4 < 32; ++k4) {
        const int kbase = k4*4;
        const int sw = fswz(kbase);           // constant over the 4 sub-ks
        const float* pa = &cA[kbase][(tm*4) ^ sw];
        const float4 q0 = *(const float4*)(pB0 + kl + kbase);
        const float4 q1 = *(const float4*)(pB1 + kl + kbase);
        const float4 q2 = *(const float4*)(pB2 + kl + kbase);
        const float4 q3 = *(const float4*)(pB3 + kl + kbase);
        #pragma unroll
        for (int u = 0; u < 4; ++u) {
          const float4 a  = *(const float4*)(pa + u*68);
          const float b0v = (u==0) ? q0.x : (u==1) ? q0.y : (u==2) ? q0.z : q0.w;
          const float b1v = (u==0) ? q1.x : (u==1) ? q1.y : (u==2) ? q1.z : q1.w;
          const float b2v = (u==0) ? q2.x : (u==1) ? q2.y : (u==2) ? q2.z : q2.w;
          const float b3v = (u==0) ? q3.x : (u==1) ? q3.y : (u==2) ? q3.z : q3.w;
          acc[0][0] = __builtin_fmaf(a.x, b0v, acc[0][0]);
          acc[1][0] = __builtin_fmaf(a.y, b0v, acc[1][0]);
          acc[2][0] = __builtin_fmaf(a.z, b0v, acc[2][0]);
          acc[3][0] = __builtin_fmaf(a.w, b0v, acc[3][0]);
          acc[0][1] = __builtin_fmaf(a.x, b1v, acc[0][1]);
          acc[1][1] = __builtin_fmaf(a.y, b1v, acc[1][1]);
          acc[2][1] = __builtin_fmaf(a.z, b1v, acc[2][1]);
          acc[3][1] = __builtin_fmaf(a.w, b1v, acc[3][1]);
          acc[0][2] = __builtin_fmaf(a.x, b2v, acc[0][2]);
          acc[1][2] = __builtin_fmaf(a.y, b2v, acc[1][2]);
          acc[2][2] = __builtin_fmaf(a.z, b2v, acc[2][2]);
          acc[3][2] = __builtin_fmaf(a.w, b2v, acc[3][2]);
          acc[0][3] = __builtin_fmaf(a.x, b3v, acc[0][3]);
          acc[1][3] = __builtin_fmaf(a.y, b3v, acc[1][3]);
          acc[2][3] = __builtin_fmaf(a.z, b3v, acc[2][3]);
          acc[3][3] = __builtin_fmaf(a.w, b3v, acc[3][3]);
        }
      }
      __syncthreads();
    }

    if (helper) {
      // ship P2 (h=0) and P3 (h=1) raw; single-buffered vs owner's consumption
      if (t >= 1) { if (tid == 0) wait_ge(&oflag[bid-1], (uint32_t)t); __syncthreads(); }
      uint64_t* pb = (uint64_t*)(partials + (size_t)hslot*8192 + (size_t)h*4096) + t256*8;
      #pragma unroll
      for (int r = 0; r < 4; ++r)
        #pragma unroll
        for (int cq = 0; cq < 2; ++cq) {
          union { float f[2]; uint64_t u; } cv;
          cv.f[0] = acc[r][cq*2+0]; cv.f[1] = acc[r][cq*2+1];
          __hip_atomic_store(&pb[r*2+cq], cv.u, __ATOMIC_RELAXED, __HIP_MEMORY_SCOPE_AGENT);
        }
      __syncthreads();
      if (tid == 0) __hip_atomic_store(&pflag[bid], (uint32_t)(t+1), __ATOMIC_RELEASE, __HIP_MEMORY_SCOPE_AGENT);
      continue;
    }

    // ---- owner in-block merge: acc = P0 + P1 (ascending, __fadd_rn)
    if (h == 1) {
      #pragma unroll
      for (int r = 0; r < 4; ++r)
        *(float4*)&ex[t256*16 + r*4] = make_float4(acc[r][0], acc[r][1], acc[r][2], acc[r][3]);
    }
    __syncthreads();
    if (h == 0) {
      #pragma unroll
      for (int r = 0; r < 4; ++r)
        #pragma unroll
        for (int c = 0; c < 4; ++c)
          acc[r][c] = __fadd_rn(acc[r][c], ex[t256*16 + r*4 + c]);
    }

    // ---- L1/L2: fold helper's P2 entirely, then P3 (same order as R5)
    if (group != 0) {
      if (tid == 0) wait_ge(&pflag[bid+1], (uint32_t)(t+1));
      __syncthreads();
      if (h == 0) {
        uint64_t* p2 = (uint64_t*)(partials + (size_t)hslot*8192) + t256*8;
        uint64_t* p3 = (uint64_t*)(partials + (size_t)hslot*8192 + 4096) + t256*8;
        #pragma unroll
        for (int r = 0; r < 4; ++r)
          #pragma unroll
          for (int cq = 0; cq < 2; ++cq) {
            union { uint64_t u; float f[2]; } cv;
            cv.u = __hip_atomic_load(&p2[r*2+cq], __ATOMIC_RELAXED, __HIP_MEMORY_SCOPE_AGENT);
            acc[r][cq*2+0] = __fadd_rn(acc[r][cq*2+0], cv.f[0]);
            acc[r][cq*2+1] = __fadd_rn(acc[r][cq*2+1], cv.f[1]);
          }
        #pragma unroll
        for (int r = 0; r < 4; ++r)
          #pragma unroll
          for (int cq = 0; cq < 2; ++cq) {
            union { uint64_t u; float f[2]; } cv;
            cv.u = __hip_atomic_load(&p3[r*2+cq], __ATOMIC_RELAXED, __HIP_MEMORY_SCOPE_AGENT);
            acc[r][cq*2+0] = __fadd_rn(acc[r][cq*2+0], cv.f[0]);
            acc[r][cq*2+1] = __fadd_rn(acc[r][cq*2+1], cv.f[1]);
          }
      }
      __syncthreads();
      if (tid == 0) __hip_atomic_store(&oflag[bid], (uint32_t)(t+1), __ATOMIC_RELEASE, __HIP_MEMORY_SCOPE_AGENT);
    }

    if (group < 2) { if (tid < 128) lBits[tid] = 0; __syncthreads(); }

    // LIF: cur = acc + b (rn); v = 0.9*v + cur (mul+add rn, NO fma contraction);
    // spk = v > 1.0 strictly; v -= spk.  (owner h=0 threads hold the full tile)
    if (h == 0) {
      float sv[4][4], vv8[4][4];
      #pragma unroll
      for (int r = 0; r < 4; ++r) {
        uint32_t msk = 0;
        #pragma unroll
        for (int c = 0; c < 4; ++c) {
          float cur = __fadd_rn(acc[r][c], bias[c]);
          float vv  = __fadd_rn(__fmul_rn(0.9f, vst[r][c]), cur);
          float s   = (vv > 1.0f) ? 1.0f : 0.0f;
          vv = __fsub_rn(vv, s);
          vst[r][c] = vv;
          sv[r][c] = s; vv8[r][c] = vv;
          msk |= (s != 0.f) ? (1u << c) : 0u;
        }
        if (group < 2 && msk)
          atomicOr(&lBits[(tm*4 + r)*2 + (tn>>3)], msk << ((tn&7)*4));
      }
      if (group == 2) {
        #pragma unroll
        for (int r = 0; r < 4; ++r) {
          size_t o  = ((size_t)(m0 + tm*4 + r)*TT + t)*DD2 + n0 + tn*4;
          *(float4*)(out + o)  = make_float4(sv[r][0], sv[r][1], sv[r][2], sv[r][3]);
          size_t ov = (size_t)NB*TT*DD2 + o;
          *(float4*)(out + ov) = make_float4(vv8[r][0], vv8[r][1], vv8[r][2], vv8[r][3]);
        }
      }
    }

    if (group < 2) {
      __syncthreads();
      if (tid < 128)
        __hip_atomic_store(&spkOut[((size_t)t*NB + m0 + (tid>>1))*64 + (n0>>5) + (tid&1)],
                           lBits[tid], __ATOMIC_RELAXED, __HIP_MEMORY_SCOPE_AGENT);
      __syncthreads();
      if (tid == 0) __hip_atomic_fetch_add(&dOut[t], 1u, __ATOMIC_RELEASE, __HIP_MEMORY_SCOPE_AGENT);
    }
  }
}

extern "C" void kernel_launch(void* const* d_in, const int* in_sizes, int n_in,
                              void* d_out, int out_size, void* d_ws, size_t ws_size,
                              hipStream_t stream) {
  (void)in_sizes; (void)n_in; (void)out_size;
  float* outf = (float*)d_out;
  if (ws_size < WS_NEED_BYTES) {            // diagnostic: absmax ~41 => ws too small
    sentinel_kernel<<<1, 1, 0, stream>>>(outf);
    return;
  }
  const float* x  = (const float*)d_in[0];
  const float* W0 = (const float*)d_in[1];
  const float* b0 = (const float*)d_in[2];
  const float* W1 = (const float*)d_in[3];
  const float* b1 = (const float*)d_in[4];
  const float* W2 = (const float*)d_in[5];
  const float* b2 = (const float*)d_in[6];
  uint32_t* ws = (uint32_t*)d_ws;

  // zero flags (spikes/partials are write-before-read; flags gate everything)
  hipMemsetAsync(ws + FLG_OFF, 0, NFLG * sizeof(uint32_t), stream);

  snn_kernel<<<256, 512, 0, stream>>>(x, W0, b0, W1, b1, W2, b2, outf, ws);
}